// Round 4
// baseline (13579.820 us; speedup 1.0000x reference)
//
#include <hip/hip_runtime.h>
#include <hip/hip_fp16.h>
#include <stdint.h>

#define S_LEN 512
#define HD 1280
#define GD 5120   // 4*C
#define VOC 32000

typedef __attribute__((ext_vector_type(8))) short short8;
typedef __attribute__((ext_vector_type(8))) _Float16 half8;
typedef __attribute__((ext_vector_type(4))) float floatx4;
typedef __attribute__((ext_vector_type(2))) _Float16 halfx2;
typedef __attribute__((ext_vector_type(4))) _Float16 halfx4;

static __device__ __forceinline__ unsigned short f2h(float f) {
  return __builtin_bit_cast(unsigned short, (_Float16)f);
}
static __device__ __forceinline__ float h2f(unsigned short h) {
  return (float)__builtin_bit_cast(_Float16, h);
}
static __device__ __forceinline__ float tanhf_fast(float x) {
  float xc = fminf(fmaxf(x, -15.f), 15.f);
  float e = __expf(2.f * xc);
  return (e - 1.f) / (e + 1.f);
}
#if __has_builtin(__builtin_amdgcn_fdot2)
static __device__ __forceinline__ float fdot2(halfx2 a, halfx2 b, float c) {
  return __builtin_amdgcn_fdot2(a, b, c, false);
}
#else
static __device__ __forceinline__ float fdot2(halfx2 a, halfx2 b, float c) {
  return c + (float)a[0]*(float)b[0] + (float)a[1]*(float)b[1];
}
#endif

// ---------------------------------------------------------------------------
// Transpose + fp32->f16 convert: in (R x C) fp32 row-major -> out (C x R) f16
// ---------------------------------------------------------------------------
__global__ __launch_bounds__(256)
void transpose_cvt(const float* __restrict__ in, unsigned short* __restrict__ out,
                   int R, int C)
{
  __shared__ float tile[32][33];
  const int c0 = blockIdx.x * 32;
  const int r0 = blockIdx.y * 32;
  const int tx = threadIdx.x & 31;
  const int ty = threadIdx.x >> 5;   // 0..7
#pragma unroll
  for (int p = 0; p < 4; p++) {
    int rl = ty + p * 8;
    tile[rl][tx] = in[(size_t)(r0 + rl) * C + c0 + tx];
  }
  __syncthreads();
#pragma unroll
  for (int p = 0; p < 4; p++) {
    int cl = ty + p * 8;
    out[(size_t)(c0 + cl) * R + r0 + tx] = f2h(tile[tx][cl]);
  }
}

// ---------------------------------------------------------------------------
// Generic MFMA GEMM (fp16 inputs, fp32 accum):
//   C(MxN) = A(MxK) * B(KxN) [B given as B^T (NxK) f16]
// CMODE: 0 = xp   (fp32 out, +bias, A rows are (b,s); out row (s',b), rev opt)
//        1 = WfT  (f16 out, transposed write out[col*M + row])
//        2 = Hcat (f16 out, A rows are (t,b); out row (b,s'), rev, +resid opt)
//        3 = logits (fp32 out, +bias, identity rows)
// AFP32: A is fp32 (converted to f16 during staging)
// ---------------------------------------------------------------------------
template<int AFP32, int CMODE>
__global__ __launch_bounds__(256, 2)
void gemm_k(const void* __restrict__ Ap, const unsigned short* __restrict__ BTp,
            void* __restrict__ Cp, const float* __restrict__ bias,
            const unsigned short* __restrict__ resid,
            int M, int N, int K, int rev)
{
  __shared__ __align__(16) short As[128 * 32];
  __shared__ __align__(16) short Bs[128 * 32];
  const int tid  = threadIdx.x;
  const int row0 = blockIdx.y * 128;
  const int col0 = blockIdx.x * 128;
  const int lane = tid & 63;
  const int wid  = tid >> 6;
  const int wrow = (wid >> 1) * 64;
  const int wcol = (wid & 1) * 64;
  const int lr   = lane & 15;
  const int gg   = lane >> 4;

  floatx4 acc[4][4];
#pragma unroll
  for (int m = 0; m < 4; m++)
#pragma unroll
    for (int n = 0; n < 4; n++)
      acc[m][n] = (floatx4)0.0f;

  for (int k0 = 0; k0 < K; k0 += 32) {
    __syncthreads();
#pragma unroll
    for (int p = 0; p < 2; p++) {
      int idx = p * 256 + tid;
      int r = idx >> 2, c = idx & 3;
      short8 va;
      if constexpr (AFP32) {
        const float* src = (const float*)Ap + (size_t)(row0 + r) * K + k0 + c * 8;
        floatx4 f0 = *(const floatx4*)src;
        floatx4 f1 = *(const floatx4*)(src + 4);
        va[0] = (short)f2h(f0[0]); va[1] = (short)f2h(f0[1]);
        va[2] = (short)f2h(f0[2]); va[3] = (short)f2h(f0[3]);
        va[4] = (short)f2h(f1[0]); va[5] = (short)f2h(f1[1]);
        va[6] = (short)f2h(f1[2]); va[7] = (short)f2h(f1[3]);
      } else {
        va = *(const short8*)((const unsigned short*)Ap + (size_t)(row0 + r) * K + k0 + c * 8);
      }
      *(short8*)&As[r * 32 + ((c ^ (r & 3)) * 8)] = va;
      short8 vb = *(const short8*)(BTp + (size_t)(col0 + r) * K + k0 + c * 8);
      *(short8*)&Bs[r * 32 + ((c ^ (r & 3)) * 8)] = vb;
    }
    __syncthreads();
    short8 af[4], bfv[4];
#pragma unroll
    for (int m = 0; m < 4; m++) {
      int r = wrow + m * 16 + lr;
      af[m] = *(const short8*)&As[r * 32 + ((gg ^ (r & 3)) * 8)];
    }
#pragma unroll
    for (int n = 0; n < 4; n++) {
      int c = wcol + n * 16 + lr;
      bfv[n] = *(const short8*)&Bs[c * 32 + ((gg ^ (c & 3)) * 8)];
    }
#pragma unroll
    for (int m = 0; m < 4; m++)
#pragma unroll
      for (int n = 0; n < 4; n++)
        acc[m][n] = __builtin_amdgcn_mfma_f32_16x16x32_f16(
            __builtin_bit_cast(half8, af[m]), __builtin_bit_cast(half8, bfv[n]),
            acc[m][n], 0, 0, 0);
  }

  // Epilogue. Verified C layout: col = lane&15, row = 4*(lane>>4) + i.
#pragma unroll
  for (int m = 0; m < 4; m++) {
    int rbase = row0 + wrow + m * 16 + 4 * gg;
#pragma unroll
    for (int n = 0; n < 4; n++) {
      int col = col0 + wcol + n * 16 + lr;
      if constexpr (CMODE == 1) {
        halfx4 t4;
#pragma unroll
        for (int i = 0; i < 4; i++) t4[i] = (_Float16)acc[m][n][i];
        *(halfx4*)((_Float16*)Cp + (size_t)col * M + rbase) = t4;
      } else if constexpr (CMODE == 0) {
        float bv = bias[col];
#pragma unroll
        for (int i = 0; i < 4; i++) {
          int r = rbase + i;
          int b = r >> 9, s = r & 511;          // A rows are (b,s)
          int so = rev ? (511 - s) : s;
          ((float*)Cp)[(size_t)((so << 1) | b) * GD + col] = acc[m][n][i] + bv;
        }
      } else if constexpr (CMODE == 2) {
#pragma unroll
        for (int i = 0; i < 4; i++) {
          int r = rbase + i;
          int t = r >> 1, b = r & 1;            // A rows (Pout) are (t,b)
          int s = rev ? (511 - t) : t;
          size_t o = (size_t)((b << 9) | s) * HD + col;
          float v = acc[m][n][i];
          if (resid) v += h2f(resid[o]);
          ((unsigned short*)Cp)[o] = f2h(v);
        }
      } else {
        float bv = bias[col];
#pragma unroll
        for (int i = 0; i < 4; i++)
          ((float*)Cp)[(size_t)(rbase + i) * N + col] = acc[m][n][i] + bv;
      }
    }
  }
}

// ---------------------------------------------------------------------------
// Persistent LSTM scan v2 (one layer, both directions).
// 256 WGs: WG = (dir = bid&1, g = bid>>1), g in [0,128). WG owns j in
// [g*10, g*10+10): 40 gate-cols (4 gates x 10 j). Weight slice lives in LDS
// (102 KB). Thread (cg = tid>>5, ks = tid&31) computes 5 cols x 40 k x 2
// batches via fdot2; full k-reduce via shfl_xor within 32-lane groups.
// Sync: 32 arrival counters per dir (4 WGs each, release RMW); waiters poll
// all 32 with relaxed wave-wide loads + one acquire fence.
// ---------------------------------------------------------------------------
__global__ __launch_bounds__(256, 1)
void lstm_scan(const _Float16* __restrict__ wfT,   // [2][GD][HD] this layer
               const float* __restrict__ xp,       // [2][1024][GD]
               unsigned short* __restrict__ Pout,  // [2][1024][HD] f16
               unsigned int* __restrict__ pbuf,    // [dir][buf][2*640] u32
               unsigned int* __restrict__ ctr,     // [2][32] shared across layers
               int tbase)
{
  const int dir = blockIdx.x & 1;
  const int g   = blockIdx.x >> 1;    // 0..127
  const int jbase = g * 10;
  const int tid = threadIdx.x;
  const int ks  = tid & 31;           // k-slice: 40 f16 at ks*40
  const int cg  = tid >> 5;           // col-group: cols cg*5 .. cg*5+4

  __shared__ __align__(16) unsigned int wlds[40 * 640];  // [col][640 u32] 102400 B
  __shared__ __align__(16) unsigned int plds[1280];      // [b][640 u32]     5120 B
  __shared__ float gvals[40][2];

  // ---- stage weight slice into LDS (once) ----
  // col c (0..39): gate q = c/10, j' = c%10 -> global row q*HD + jbase + j'
#pragma unroll 1
  for (int i = 0; i < 25; i++) {
    int idx = i * 256 + tid;          // 16B-chunk index, 6400 total
    int c = idx / 160, r = idx - c * 160;
    size_t rowIdx = (size_t)dir * GD + (c / 10) * HD + jbase + (c % 10);
    const uint4* src = (const uint4*)(wfT + rowIdx * HD);
    *(uint4*)&wlds[c * 640 + r * 4] = src[r];
  }

  // precompute this thread's 5 gate-column global indices
  int gcol[5];
#pragma unroll
  for (int i = 0; i < 5; i++) {
    int c = cg * 5 + i;
    gcol[i] = (c / 10) * HD + jbase + (c % 10);
  }
  const bool isRed = (ks == 0);

  const bool isOwn = tid < 20;
  const int oj = tid >> 1, ob = tid & 1;
  float cst = 0.f;

  __syncthreads();   // weights staged

  for (int t = 0; t < S_LEN; t++) {
    // prefetch xp[t] (independent of p) so latency hides under the poll
    float xpv[5][2];
    if (isRed) {
#pragma unroll
      for (int i = 0; i < 5; i++)
#pragma unroll
        for (int b = 0; b < 2; b++)
          xpv[i][b] = xp[((size_t)dir * 1024 + t * 2 + b) * GD + gcol[i]];
    }

    // wait for p(t-1): all 32 counters must reach (tbase+t)*4
    if (t > 0) {
      if (tid < 64) {
        const unsigned tgt = (unsigned)(tbase + t) * 4u;
        const unsigned int* cp = ctr + dir * 32 + (tid & 31);
        while (true) {
          unsigned v = __hip_atomic_load(cp, __ATOMIC_RELAXED, __HIP_MEMORY_SCOPE_AGENT);
          if (__all(v >= tgt)) break;
          __builtin_amdgcn_s_sleep(1);
        }
        __builtin_amdgcn_fence(__ATOMIC_ACQUIRE, "agent");
      }
      __syncthreads();
    }

    // stage p(t-1) into LDS: 1280 u32, coalesced relaxed loads
    const unsigned int* pr = pbuf + (dir * 2 + (t & 1)) * 1280;
#pragma unroll
    for (int r = 0; r < 5; r++)
      plds[r * 256 + tid] = __hip_atomic_load(pr + r * 256 + tid,
                                              __ATOMIC_RELAXED, __HIP_MEMORY_SCOPE_AGENT);
    __syncthreads();

    // compute: 5 cols x 40 k x 2 batches of fdot2, weights+p from LDS
    float acc[5][2];
#pragma unroll
    for (int i = 0; i < 5; i++) { acc[i][0] = 0.f; acc[i][1] = 0.f; }
#pragma unroll
    for (int j = 0; j < 5; j++) {     // 5 chunks of 8 f16 along k
      half8 pv0 = *(const half8*)&plds[0 * 640 + ks * 20 + j * 4];
      half8 pv1 = *(const half8*)&plds[1 * 640 + ks * 20 + j * 4];
#pragma unroll
      for (int i = 0; i < 5; i++) {
        half8 wv = *(const half8*)&wlds[(cg * 5 + i) * 640 + ks * 20 + j * 4];
#pragma unroll
        for (int u = 0; u < 4; u++) {
          halfx2 w2  = {wv[2 * u], wv[2 * u + 1]};
          halfx2 p02 = {pv0[2 * u], pv0[2 * u + 1]};
          halfx2 p12 = {pv1[2 * u], pv1[2 * u + 1]};
          acc[i][0] = fdot2(p02, w2, acc[i][0]);
          acc[i][1] = fdot2(p12, w2, acc[i][1]);
        }
      }
    }

    // full k reduction across the 32 lanes of each half-wave
#pragma unroll
    for (int i = 0; i < 5; i++)
#pragma unroll
      for (int b = 0; b < 2; b++) {
        float v = acc[i][b];
#pragma unroll
        for (int off = 16; off >= 1; off >>= 1)
          v += __shfl_xor(v, off, 32);
        if (isRed) gvals[cg * 5 + i][b] = v + xpv[i][b];
      }
    __syncthreads();

    // owners: cell update + publish p'
    if (isOwn) {
      float gi = gvals[oj][ob];
      float gf = gvals[10 + oj][ob];
      float gz = gvals[20 + oj][ob];
      float go = gvals[30 + oj][ob];
      float si = 1.f / (1.f + __expf(-gi));
      float sf = 1.f / (1.f + __expf(-gf));
      float so = 1.f / (1.f + __expf(-go));
      float tz = tanhf_fast(gz);
      cst = si * tz + sf * cst;
      float pv = so * tanhf_fast(cst);
      unsigned int* pw = pbuf + (dir * 2 + ((t + 1) & 1)) * 1280;
      ((unsigned short*)pw)[ob * HD + jbase + oj] = f2h(pv);
      Pout[((size_t)dir * 1024 + t * 2 + ob) * HD + jbase + oj] = f2h(pv);
    }
    __syncthreads();   // drains owners' stores before release add
    if (tid == 0) {
      __hip_atomic_fetch_add(ctr + dir * 32 + (g & 31), 1u,
                             __ATOMIC_RELEASE, __HIP_MEMORY_SCOPE_AGENT);
    }
  }
}

// ---------------------------------------------------------------------------
extern "C" void kernel_launch(void* const* d_in, const int* in_sizes, int n_in,
                              void* d_out, int out_size, void* d_ws, size_t ws_size,
                              hipStream_t stream)
{
  char* W = (char*)d_ws;
  // workspace layout (bytes) — all 2-byte planes are f16
  const size_t WS_T  = 0;                    // Ws^T f16 [4][GD][HD]    52,428,800
  const size_t WI_T  = 52428800;             // Wi^T f16 [4][GD][HD]    52,428,800
  const size_t WP_T  = 104857600;            // Wp^T f16 [4][HD][HD]    13,107,200
  const size_t WF_T  = 117964800;            // Wf^T f16 [4][GD][HD]    52,428,800
  const size_t HCAT  = 170393600;            // f16 [4096][HD]          10,485,760
  const size_t P_O   = 180879360;            // f16 [2][1024][HD]        5,242,880
  const size_t XP_O  = 186122240;            // f32 [2][1024][GD]       41,943,040
  const size_t PB_O  = 228065280;            // u32 [2 lay][2 dir][2 buf][1280]  40,960
  const size_t CTR_O = 228106240;            // u32 [2 dir][32]              256
  const size_t NEED  = 228106496;
  const size_t WLIN_T = 0;                   // alias over WS_T/WI_T (dead by then)
  if (ws_size < NEED) return;

  const float* x    = (const float*)d_in[0];
  const float* Wi_f = (const float*)d_in[1];
  const float* Ws_f = (const float*)d_in[2];
  const float* b_f  = (const float*)d_in[3];
  const float* Wp_f = (const float*)d_in[4];
  const float* Wi_b = (const float*)d_in[5];
  const float* Ws_b = (const float*)d_in[6];
  const float* b_b  = (const float*)d_in[7];
  const float* Wp_b = (const float*)d_in[8];
  const float* Wlin = (const float*)d_in[9];
  const float* blin = (const float*)d_in[10];

  hipMemsetAsync(W + PB_O, 0, 40960 + 256, stream);

  // weight transposes (+f16)
  for (int l = 0; l < 2; l++)
    for (int d = 0; d < 2; d++) {
      int ld = l * 2 + d;
      const float* ws_src = (d ? Ws_b : Ws_f) + (size_t)l * HD * GD;
      const float* wi_src = (d ? Wi_b : Wi_f) + (size_t)l * HD * GD;
      const float* wp_src = (d ? Wp_b : Wp_f) + (size_t)l * HD * HD;
      transpose_cvt<<<dim3(GD / 32, HD / 32), 256, 0, stream>>>(
        ws_src, (unsigned short*)(W + WS_T) + (size_t)ld * GD * HD, HD, GD);
      transpose_cvt<<<dim3(GD / 32, HD / 32), 256, 0, stream>>>(
        wi_src, (unsigned short*)(W + WI_T) + (size_t)ld * GD * HD, HD, GD);
      transpose_cvt<<<dim3(HD / 32, HD / 32), 256, 0, stream>>>(
        wp_src, (unsigned short*)(W + WP_T) + (size_t)ld * HD * HD, HD, HD);
    }

  // Wf = Wp @ Ws, written transposed as f16
  for (int l = 0; l < 2; l++)
    for (int d = 0; d < 2; d++) {
      int ld = l * 2 + d;
      const float* wp_src = (d ? Wp_b : Wp_f) + (size_t)l * HD * HD;
      gemm_k<1, 1><<<dim3(GD / 128, HD / 128), 256, 0, stream>>>(
        wp_src, (const unsigned short*)(W + WS_T) + (size_t)ld * GD * HD,
        (void*)((_Float16*)(W + WF_T) + (size_t)ld * GD * HD),
        nullptr, nullptr, HD, GD, HD, 0);
    }

  for (int l = 0; l < 2; l++) {
    // xp = in @ Wi + b  (time-reversed rows for bwd)
    for (int d = 0; d < 2; d++) {
      int ld = l * 2 + d;
      const float* bias = (d ? b_b : b_f) + (size_t)l * GD;
      if (l == 0) {
        gemm_k<1, 0><<<dim3(GD / 128, 1024 / 128), 256, 0, stream>>>(
          x, (const unsigned short*)(W + WI_T) + (size_t)ld * GD * HD,
          (void*)((float*)(W + XP_O) + (size_t)d * 1024 * GD),
          bias, nullptr, 1024, GD, HD, d);
      } else {
        const unsigned short* Ain =
          (const unsigned short*)(W + HCAT) + (size_t)(d * 2048 + (l - 1) * 1024) * HD;
        gemm_k<0, 0><<<dim3(GD / 128, 1024 / 128), 256, 0, stream>>>(
          Ain, (const unsigned short*)(W + WI_T) + (size_t)ld * GD * HD,
          (void*)((float*)(W + XP_O) + (size_t)d * 1024 * GD),
          bias, nullptr, 1024, GD, HD, d);
      }
    }
    if (l == 1) {
      // WS_T / WI_T regions are dead now: build W_lin^T in their place
      transpose_cvt<<<dim3(VOC / 32, HD / 32), 256, 0, stream>>>(
        Wlin, (unsigned short*)(W + WLIN_T), HD, VOC);
    }
    // recurrence
    lstm_scan<<<256, 256, 0, stream>>>(
      (const _Float16*)(W + WF_T) + (size_t)l * 2 * GD * HD,
      (const float*)(W + XP_O),
      (unsigned short*)(W + P_O),
      (unsigned int*)(W + PB_O) + (size_t)l * 5120,
      (unsigned int*)(W + CTR_O),
      l * 512);
    // ys = P @ Wp (+ residual for l>0) -> Hcat slice (b,s) rows
    for (int d = 0; d < 2; d++) {
      int ld = l * 2 + d;
      const unsigned short* resid = (l == 0) ? nullptr :
        (const unsigned short*)(W + HCAT) + (size_t)(d * 2048 + (l - 1) * 1024) * HD;
      gemm_k<0, 2><<<dim3(HD / 128, 1024 / 128), 256, 0, stream>>>(
        (const unsigned short*)(W + P_O) + (size_t)d * 1024 * HD,
        (const unsigned short*)(W + WP_T) + (size_t)ld * HD * HD,
        (void*)((unsigned short*)(W + HCAT) + (size_t)(d * 2048 + l * 1024) * HD),
        nullptr, resid, 1024, HD, HD, d);
    }
  }

  // logits = Hcat @ W_lin + b_lin  -> d_out (rows already in required order)
  gemm_k<0, 3><<<dim3(VOC / 128, 4096 / 128), 256, 0, stream>>>(
    (const unsigned short*)(W + HCAT), (const unsigned short*)(W + WLIN_T),
    d_out, blin, nullptr, 4096, VOC, HD, 0);
}

// Round 5
// 7255.748 us; speedup vs baseline: 1.8716x; 1.8716x over previous
//
#include <hip/hip_runtime.h>
#include <hip/hip_fp16.h>
#include <stdint.h>

#define S_LEN 512
#define HD 1280
#define GD 5120   // 4*C
#define VOC 32000

typedef __attribute__((ext_vector_type(8))) short short8;
typedef __attribute__((ext_vector_type(8))) _Float16 half8;
typedef __attribute__((ext_vector_type(4))) float floatx4;
typedef __attribute__((ext_vector_type(2))) _Float16 halfx2;
typedef __attribute__((ext_vector_type(4))) _Float16 halfx4;

static __device__ __forceinline__ unsigned short f2h(float f) {
  return __builtin_bit_cast(unsigned short, (_Float16)f);
}
static __device__ __forceinline__ float h2f(unsigned short h) {
  return (float)__builtin_bit_cast(_Float16, h);
}
static __device__ __forceinline__ float tanhf_fast(float x) {
  float xc = fminf(fmaxf(x, -15.f), 15.f);
  float e = __expf(2.f * xc);
  return (e - 1.f) / (e + 1.f);
}
#if __has_builtin(__builtin_amdgcn_fdot2)
static __device__ __forceinline__ float fdot2(halfx2 a, halfx2 b, float c) {
  return __builtin_amdgcn_fdot2(a, b, c, false);
}
#else
static __device__ __forceinline__ float fdot2(halfx2 a, halfx2 b, float c) {
  return c + (float)a[0]*(float)b[0] + (float)a[1]*(float)b[1];
}
#endif

// ---------------------------------------------------------------------------
// Transpose + fp32->f16 convert: in (R x C) fp32 row-major -> out (C x R) f16
// ---------------------------------------------------------------------------
__global__ __launch_bounds__(256)
void transpose_cvt(const float* __restrict__ in, unsigned short* __restrict__ out,
                   int R, int C)
{
  __shared__ float tile[32][33];
  const int c0 = blockIdx.x * 32;
  const int r0 = blockIdx.y * 32;
  const int tx = threadIdx.x & 31;
  const int ty = threadIdx.x >> 5;   // 0..7
#pragma unroll
  for (int p = 0; p < 4; p++) {
    int rl = ty + p * 8;
    tile[rl][tx] = in[(size_t)(r0 + rl) * C + c0 + tx];
  }
  __syncthreads();
#pragma unroll
  for (int p = 0; p < 4; p++) {
    int cl = ty + p * 8;
    out[(size_t)(c0 + cl) * R + r0 + tx] = f2h(tile[tx][cl]);
  }
}

// ---------------------------------------------------------------------------
// Generic MFMA GEMM (fp16 inputs, fp32 accum):
//   C(MxN) = A(MxK) * B(KxN) [B given as B^T (NxK) f16]
// CMODE: 0 = xp   (fp32 out, +bias, A rows are (b,s); out row (s',b), rev opt)
//        1 = WfT  (f16 out, transposed write out[col*M + row])
//        2 = Hcat (f16 out, A rows are (t,b); out row (b,s'), rev, +resid opt)
//        3 = logits (fp32 out, +bias, identity rows)
// AFP32: A is fp32 (converted to f16 during staging)
// ---------------------------------------------------------------------------
template<int AFP32, int CMODE>
__global__ __launch_bounds__(256, 2)
void gemm_k(const void* __restrict__ Ap, const unsigned short* __restrict__ BTp,
            void* __restrict__ Cp, const float* __restrict__ bias,
            const unsigned short* __restrict__ resid,
            int M, int N, int K, int rev)
{
  __shared__ __align__(16) short As[128 * 32];
  __shared__ __align__(16) short Bs[128 * 32];
  const int tid  = threadIdx.x;
  const int row0 = blockIdx.y * 128;
  const int col0 = blockIdx.x * 128;
  const int lane = tid & 63;
  const int wid  = tid >> 6;
  const int wrow = (wid >> 1) * 64;
  const int wcol = (wid & 1) * 64;
  const int lr   = lane & 15;
  const int gg   = lane >> 4;

  floatx4 acc[4][4];
#pragma unroll
  for (int m = 0; m < 4; m++)
#pragma unroll
    for (int n = 0; n < 4; n++)
      acc[m][n] = (floatx4)0.0f;

  for (int k0 = 0; k0 < K; k0 += 32) {
    __syncthreads();
#pragma unroll
    for (int p = 0; p < 2; p++) {
      int idx = p * 256 + tid;
      int r = idx >> 2, c = idx & 3;
      short8 va;
      if constexpr (AFP32) {
        const float* src = (const float*)Ap + (size_t)(row0 + r) * K + k0 + c * 8;
        floatx4 f0 = *(const floatx4*)src;
        floatx4 f1 = *(const floatx4*)(src + 4);
        va[0] = (short)f2h(f0[0]); va[1] = (short)f2h(f0[1]);
        va[2] = (short)f2h(f0[2]); va[3] = (short)f2h(f0[3]);
        va[4] = (short)f2h(f1[0]); va[5] = (short)f2h(f1[1]);
        va[6] = (short)f2h(f1[2]); va[7] = (short)f2h(f1[3]);
      } else {
        va = *(const short8*)((const unsigned short*)Ap + (size_t)(row0 + r) * K + k0 + c * 8);
      }
      *(short8*)&As[r * 32 + ((c ^ (r & 3)) * 8)] = va;
      short8 vb = *(const short8*)(BTp + (size_t)(col0 + r) * K + k0 + c * 8);
      *(short8*)&Bs[r * 32 + ((c ^ (r & 3)) * 8)] = vb;
    }
    __syncthreads();
    short8 af[4], bfv[4];
#pragma unroll
    for (int m = 0; m < 4; m++) {
      int r = wrow + m * 16 + lr;
      af[m] = *(const short8*)&As[r * 32 + ((gg ^ (r & 3)) * 8)];
    }
#pragma unroll
    for (int n = 0; n < 4; n++) {
      int c = wcol + n * 16 + lr;
      bfv[n] = *(const short8*)&Bs[c * 32 + ((gg ^ (c & 3)) * 8)];
    }
#pragma unroll
    for (int m = 0; m < 4; m++)
#pragma unroll
      for (int n = 0; n < 4; n++)
        acc[m][n] = __builtin_amdgcn_mfma_f32_16x16x32_f16(
            __builtin_bit_cast(half8, af[m]), __builtin_bit_cast(half8, bfv[n]),
            acc[m][n], 0, 0, 0);
  }

  // Epilogue. Verified C layout: col = lane&15, row = 4*(lane>>4) + i.
#pragma unroll
  for (int m = 0; m < 4; m++) {
    int rbase = row0 + wrow + m * 16 + 4 * gg;
#pragma unroll
    for (int n = 0; n < 4; n++) {
      int col = col0 + wcol + n * 16 + lr;
      if constexpr (CMODE == 1) {
        halfx4 t4;
#pragma unroll
        for (int i = 0; i < 4; i++) t4[i] = (_Float16)acc[m][n][i];
        *(halfx4*)((_Float16*)Cp + (size_t)col * M + rbase) = t4;
      } else if constexpr (CMODE == 0) {
        float bv = bias[col];
#pragma unroll
        for (int i = 0; i < 4; i++) {
          int r = rbase + i;
          int b = r >> 9, s = r & 511;          // A rows are (b,s)
          int so = rev ? (511 - s) : s;
          ((float*)Cp)[(size_t)((so << 1) | b) * GD + col] = acc[m][n][i] + bv;
        }
      } else if constexpr (CMODE == 2) {
#pragma unroll
        for (int i = 0; i < 4; i++) {
          int r = rbase + i;
          int t = r >> 1, b = r & 1;            // A rows (Pout) are (t,b)
          int s = rev ? (511 - t) : t;
          size_t o = (size_t)((b << 9) | s) * HD + col;
          float v = acc[m][n][i];
          if (resid) v += h2f(resid[o]);
          ((unsigned short*)Cp)[o] = f2h(v);
        }
      } else {
        float bv = bias[col];
#pragma unroll
        for (int i = 0; i < 4; i++)
          ((float*)Cp)[(size_t)(rbase + i) * N + col] = acc[m][n][i] + bv;
      }
    }
  }
}

// ---------------------------------------------------------------------------
// Persistent LSTM scan v3 (one layer, both directions) — FENCE-FREE protocol.
// All cross-WG data (p', counters) moves via relaxed AGENT-scope atomics
// (sc-flagged, write-through to the coherence point). No acquire/release
// fences -> no per-step buffer_inv / buffer_wbl2 (L2-wide maintenance).
// Producer order: atomic p' stores -> s_waitcnt vmcnt(0) -> relaxed RMW.
// Consumer order: relaxed ctr poll -> __syncthreads -> relaxed p loads.
// Owners: 10 threads, each (j-pair, batch), publish one packed u32.
// ---------------------------------------------------------------------------
__global__ __launch_bounds__(256, 1)
void lstm_scan(const _Float16* __restrict__ wfT,   // [2][GD][HD] this layer
               const float* __restrict__ xp,       // [2][1024][GD]
               unsigned short* __restrict__ Pout,  // [2][1024][HD] f16
               unsigned int* __restrict__ pbuf,    // [dir][buf][2][640] u32
               unsigned int* __restrict__ ctr,     // [2][32] shared across layers
               int tbase)
{
  const int dir = blockIdx.x & 1;
  const int g   = blockIdx.x >> 1;    // 0..127
  const int jbase = g * 10;
  const int tid = threadIdx.x;
  const int ks  = tid & 31;           // k-slice: 40 f16 at ks*40
  const int cg  = tid >> 5;           // col-group: cols cg*5 .. cg*5+4

  __shared__ __align__(16) unsigned int wlds[40 * 640];  // [col][640 u32] 102400 B
  __shared__ __align__(16) unsigned int plds[1280];      // [b][640 u32]     5120 B
  __shared__ float gvals[40][2];

  // ---- stage weight slice into LDS (once) ----
#pragma unroll 1
  for (int i = 0; i < 25; i++) {
    int idx = i * 256 + tid;          // 16B-chunk index, 6400 total
    int c = idx / 160, r = idx - c * 160;
    size_t rowIdx = (size_t)dir * GD + (c / 10) * HD + jbase + (c % 10);
    const uint4* src = (const uint4*)(wfT + rowIdx * HD);
    *(uint4*)&wlds[c * 640 + r * 4] = src[r];
  }

  int gcol[5];
#pragma unroll
  for (int i = 0; i < 5; i++) {
    int c = cg * 5 + i;
    gcol[i] = (c / 10) * HD + jbase + (c % 10);
  }
  const bool isRed = (ks == 0);

  const bool isOwn = tid < 10;
  const int ob = tid & 1;             // batch
  const int op = tid >> 1;            // j-pair 0..4 (j = op*2, op*2+1)
  float cst0 = 0.f, cst1 = 0.f;

  __syncthreads();   // weights staged

  for (int t = 0; t < S_LEN; t++) {
    // prefetch xp[t] (independent of p) so latency hides under the poll
    float xpv[5][2];
    if (isRed) {
#pragma unroll
      for (int i = 0; i < 5; i++)
#pragma unroll
        for (int b = 0; b < 2; b++)
          xpv[i][b] = xp[((size_t)dir * 1024 + t * 2 + b) * GD + gcol[i]];
    }

    // wait for p(t-1): all 32 counters must reach (tbase+t)*4 (relaxed poll)
    if (t > 0) {
      if (tid < 64) {
        const unsigned tgt = (unsigned)(tbase + t) * 4u;
        const unsigned int* cp = ctr + dir * 32 + (tid & 31);
        while (true) {
          unsigned v = __hip_atomic_load(cp, __ATOMIC_RELAXED, __HIP_MEMORY_SCOPE_AGENT);
          if (__all(v >= tgt)) break;
          __builtin_amdgcn_s_sleep(1);
        }
      }
      __syncthreads();
    }

    // stage p(t-1) into LDS: 1280 u32, coalesced relaxed agent loads
    const unsigned int* pr = pbuf + (dir * 2 + (t & 1)) * 1280;
#pragma unroll
    for (int r = 0; r < 5; r++)
      plds[r * 256 + tid] = __hip_atomic_load(pr + r * 256 + tid,
                                              __ATOMIC_RELAXED, __HIP_MEMORY_SCOPE_AGENT);
    __syncthreads();

    // compute: 5 cols x 40 k x 2 batches of fdot2, weights+p from LDS
    float acc[5][2];
#pragma unroll
    for (int i = 0; i < 5; i++) { acc[i][0] = 0.f; acc[i][1] = 0.f; }
#pragma unroll
    for (int j = 0; j < 5; j++) {     // 5 chunks of 8 f16 along k
      half8 pv0 = *(const half8*)&plds[0 * 640 + ks * 20 + j * 4];
      half8 pv1 = *(const half8*)&plds[1 * 640 + ks * 20 + j * 4];
#pragma unroll
      for (int i = 0; i < 5; i++) {
        half8 wv = *(const half8*)&wlds[(cg * 5 + i) * 640 + ks * 20 + j * 4];
#pragma unroll
        for (int u = 0; u < 4; u++) {
          halfx2 w2  = {wv[2 * u], wv[2 * u + 1]};
          halfx2 p02 = {pv0[2 * u], pv0[2 * u + 1]};
          halfx2 p12 = {pv1[2 * u], pv1[2 * u + 1]};
          acc[i][0] = fdot2(p02, w2, acc[i][0]);
          acc[i][1] = fdot2(p12, w2, acc[i][1]);
        }
      }
    }

    // full k reduction across the 32 lanes of each half-wave
#pragma unroll
    for (int i = 0; i < 5; i++)
#pragma unroll
      for (int b = 0; b < 2; b++) {
        float v = acc[i][b];
#pragma unroll
        for (int off = 16; off >= 1; off >>= 1)
          v += __shfl_xor(v, off, 32);
        if (isRed) gvals[cg * 5 + i][b] = v + xpv[i][b];
      }
    __syncthreads();

    // owners: cell update for j-pair (op*2, op*2+1), batch ob; publish packed u32
    if (isOwn) {
      int j0 = op * 2, j1 = op * 2 + 1;
      float gi0 = gvals[j0][ob],      gi1 = gvals[j1][ob];
      float gf0 = gvals[10 + j0][ob], gf1 = gvals[10 + j1][ob];
      float gz0 = gvals[20 + j0][ob], gz1 = gvals[20 + j1][ob];
      float go0 = gvals[30 + j0][ob], go1 = gvals[30 + j1][ob];
      float si0 = 1.f / (1.f + __expf(-gi0)), si1 = 1.f / (1.f + __expf(-gi1));
      float sf0 = 1.f / (1.f + __expf(-gf0)), sf1 = 1.f / (1.f + __expf(-gf1));
      float so0 = 1.f / (1.f + __expf(-go0)), so1 = 1.f / (1.f + __expf(-go1));
      cst0 = si0 * tanhf_fast(gz0) + sf0 * cst0;
      cst1 = si1 * tanhf_fast(gz1) + sf1 * cst1;
      float pv0 = so0 * tanhf_fast(cst0);
      float pv1 = so1 * tanhf_fast(cst1);
      unsigned int packed = (unsigned)f2h(pv0) | ((unsigned)f2h(pv1) << 16);
      unsigned int* pw = pbuf + (dir * 2 + ((t + 1) & 1)) * 1280;
      __hip_atomic_store(pw + ob * 640 + (jbase >> 1) + op, packed,
                         __ATOMIC_RELAXED, __HIP_MEMORY_SCOPE_AGENT);
      ((unsigned int*)Pout)[(((size_t)dir * 1024 + t * 2 + ob) * HD + jbase) / 2 + op] = packed;
    }
    // producer ordering: p' stores complete before counter RMW (same wave)
    asm volatile("s_waitcnt vmcnt(0)" ::: "memory");
    if (tid == 0) {
      __hip_atomic_fetch_add(ctr + dir * 32 + (g & 31), 1u,
                             __ATOMIC_RELAXED, __HIP_MEMORY_SCOPE_AGENT);
    }
  }
}

// ---------------------------------------------------------------------------
extern "C" void kernel_launch(void* const* d_in, const int* in_sizes, int n_in,
                              void* d_out, int out_size, void* d_ws, size_t ws_size,
                              hipStream_t stream)
{
  char* W = (char*)d_ws;
  // workspace layout (bytes) — all 2-byte planes are f16
  const size_t WS_T  = 0;                    // Ws^T f16 [4][GD][HD]    52,428,800
  const size_t WI_T  = 52428800;             // Wi^T f16 [4][GD][HD]    52,428,800
  const size_t WP_T  = 104857600;            // Wp^T f16 [4][HD][HD]    13,107,200
  const size_t WF_T  = 117964800;            // Wf^T f16 [4][GD][HD]    52,428,800
  const size_t HCAT  = 170393600;            // f16 [4096][HD]          10,485,760
  const size_t P_O   = 180879360;            // f16 [2][1024][HD]        5,242,880
  const size_t XP_O  = 186122240;            // f32 [2][1024][GD]       41,943,040
  const size_t PB_O  = 228065280;            // u32 [2 lay][2 dir][2 buf][1280]  40,960
  const size_t CTR_O = 228106240;            // u32 [2 dir][32]              256
  const size_t NEED  = 228106496;
  const size_t WLIN_T = 0;                   // alias over WS_T/WI_T (dead by then)
  if (ws_size < NEED) return;

  const float* x    = (const float*)d_in[0];
  const float* Wi_f = (const float*)d_in[1];
  const float* Ws_f = (const float*)d_in[2];
  const float* b_f  = (const float*)d_in[3];
  const float* Wp_f = (const float*)d_in[4];
  const float* Wi_b = (const float*)d_in[5];
  const float* Ws_b = (const float*)d_in[6];
  const float* b_b  = (const float*)d_in[7];
  const float* Wp_b = (const float*)d_in[8];
  const float* Wlin = (const float*)d_in[9];
  const float* blin = (const float*)d_in[10];

  hipMemsetAsync(W + PB_O, 0, 40960 + 256, stream);

  // weight transposes (+f16)
  for (int l = 0; l < 2; l++)
    for (int d = 0; d < 2; d++) {
      int ld = l * 2 + d;
      const float* ws_src = (d ? Ws_b : Ws_f) + (size_t)l * HD * GD;
      const float* wi_src = (d ? Wi_b : Wi_f) + (size_t)l * HD * GD;
      const float* wp_src = (d ? Wp_b : Wp_f) + (size_t)l * HD * HD;
      transpose_cvt<<<dim3(GD / 32, HD / 32), 256, 0, stream>>>(
        ws_src, (unsigned short*)(W + WS_T) + (size_t)ld * GD * HD, HD, GD);
      transpose_cvt<<<dim3(GD / 32, HD / 32), 256, 0, stream>>>(
        wi_src, (unsigned short*)(W + WI_T) + (size_t)ld * GD * HD, HD, GD);
      transpose_cvt<<<dim3(HD / 32, HD / 32), 256, 0, stream>>>(
        wp_src, (unsigned short*)(W + WP_T) + (size_t)ld * HD * HD, HD, HD);
    }

  // Wf = Wp @ Ws, written transposed as f16
  for (int l = 0; l < 2; l++)
    for (int d = 0; d < 2; d++) {
      int ld = l * 2 + d;
      const float* wp_src = (d ? Wp_b : Wp_f) + (size_t)l * HD * HD;
      gemm_k<1, 1><<<dim3(GD / 128, HD / 128), 256, 0, stream>>>(
        wp_src, (const unsigned short*)(W + WS_T) + (size_t)ld * GD * HD,
        (void*)((_Float16*)(W + WF_T) + (size_t)ld * GD * HD),
        nullptr, nullptr, HD, GD, HD, 0);
    }

  for (int l = 0; l < 2; l++) {
    // xp = in @ Wi + b  (time-reversed rows for bwd)
    for (int d = 0; d < 2; d++) {
      int ld = l * 2 + d;
      const float* bias = (d ? b_b : b_f) + (size_t)l * GD;
      if (l == 0) {
        gemm_k<1, 0><<<dim3(GD / 128, 1024 / 128), 256, 0, stream>>>(
          x, (const unsigned short*)(W + WI_T) + (size_t)ld * GD * HD,
          (void*)((float*)(W + XP_O) + (size_t)d * 1024 * GD),
          bias, nullptr, 1024, GD, HD, d);
      } else {
        const unsigned short* Ain =
          (const unsigned short*)(W + HCAT) + (size_t)(d * 2048 + (l - 1) * 1024) * HD;
        gemm_k<0, 0><<<dim3(GD / 128, 1024 / 128), 256, 0, stream>>>(
          Ain, (const unsigned short*)(W + WI_T) + (size_t)ld * GD * HD,
          (void*)((float*)(W + XP_O) + (size_t)d * 1024 * GD),
          bias, nullptr, 1024, GD, HD, d);
      }
    }
    if (l == 1) {
      // WS_T / WI_T regions are dead now: build W_lin^T in their place
      transpose_cvt<<<dim3(VOC / 32, HD / 32), 256, 0, stream>>>(
        Wlin, (unsigned short*)(W + WLIN_T), HD, VOC);
    }
    // recurrence
    lstm_scan<<<256, 256, 0, stream>>>(
      (const _Float16*)(W + WF_T) + (size_t)l * 2 * GD * HD,
      (const float*)(W + XP_O),
      (unsigned short*)(W + P_O),
      (unsigned int*)(W + PB_O) + (size_t)l * 5120,
      (unsigned int*)(W + CTR_O),
      l * 512);
    // ys = P @ Wp (+ residual for l>0) -> Hcat slice (b,s) rows
    for (int d = 0; d < 2; d++) {
      int ld = l * 2 + d;
      const unsigned short* resid = (l == 0) ? nullptr :
        (const unsigned short*)(W + HCAT) + (size_t)(d * 2048 + (l - 1) * 1024) * HD;
      gemm_k<0, 2><<<dim3(HD / 128, 1024 / 128), 256, 0, stream>>>(
        (const unsigned short*)(W + P_O) + (size_t)d * 1024 * HD,
        (const unsigned short*)(W + WP_T) + (size_t)ld * HD * HD,
        (void*)((unsigned short*)(W + HCAT) + (size_t)(d * 2048 + l * 1024) * HD),
        nullptr, resid, 1024, HD, HD, d);
    }
  }

  // logits = Hcat @ W_lin + b_lin  -> d_out (rows already in required order)
  gemm_k<0, 3><<<dim3(VOC / 128, 4096 / 128), 256, 0, stream>>>(
    (const unsigned short*)(W + HCAT), (const unsigned short*)(W + WLIN_T),
    d_out, blin, nullptr, 4096, VOC, HD, 0);
}